// Round 7
// baseline (3141.590 us; speedup 1.0000x reference)
//
#include <hip/hip_runtime.h>
#include <math.h>

// ---------------------------------------------------------------------------
// GNN TLearner forward, MI355X.
// R6: (1) rank-based CSR fill — k_count records rank[e]=atomic ordinal, fill
//     becomes atomic-free; (2) nodeA+nodeB fused (femb never materialized,
//     -45MB traffic); (3) float4 LDS weight reads in node kernel.
//
// Algebra (audited R3): peer MLP folded to node level; 2-hop deg_inv factored;
// relu(f_emb) dropped (all components >=0); deg = rowstart[v+1]-rowstart[v].
//
// Tier 1 (rank): memset(counts) -> k_count(+rank) -> k_scan -> k_fillR
//                -> k_aggP1 -> k_aggP2 -> k_nodeAB
// Tier 2 (R5):   cursor+atomic fill variant.   Tier 3: pure-atomic edges.
//
// Tier1 ws (4B elems): counts[N] | rowstart[N+4] | rank[E] (align16)
//                      | payload[4E] | eagg[16N] | easum[2N] | h2[16N]
// out layout (floats): y0[N] | y1[N] | emb[64N]
// ---------------------------------------------------------------------------

// ============================ CSR-build kernels ============================

// count in-degree AND record each edge's ordinal within its dst segment
__global__ void k_countR(const int* __restrict__ dst, int* __restrict__ counts,
                         int* __restrict__ rank, int nE) {
    int e = blockIdx.x * blockDim.x + threadIdx.x;
    if (e < nE) rank[e] = atomicAdd(&counts[dst[e]], 1);
}

__global__ void k_count(const int* __restrict__ dst, int* __restrict__ counts,
                        int nE) {
    int e = blockIdx.x * blockDim.x + threadIdx.x;
    if (e < nE) atomicAdd(&counts[dst[e]], 1);
}

// single-workgroup exclusive scan of counts[0..nN) -> rowstart (& cursor)
template <bool WRITE_CURSOR>
__global__ __launch_bounds__(1024) void k_scan(const int* __restrict__ counts,
                                               int* __restrict__ rowstart,
                                               int* __restrict__ cursor,
                                               int nN, int nE) {
    __shared__ int s[1024];
    int t = threadIdx.x;
    int C = (nN + 1023) / 1024;
    int lo = min(t * C, nN), hi = min(lo + C, nN);
    int sum = 0;
    for (int i = lo; i < hi; ++i) sum += counts[i];
    s[t] = sum;
    __syncthreads();
    for (int off = 1; off < 1024; off <<= 1) {
        int v = (t >= off) ? s[t - off] : 0;
        __syncthreads();
        s[t] += v;
        __syncthreads();
    }
    int run = (t == 0) ? 0 : s[t - 1];
    for (int i = lo; i < hi; ++i) {
        rowstart[i] = run;
        if (WRITE_CURSOR) cursor[i] = run;
        run += counts[i];
    }
    if (t == 0) rowstart[nN] = nE;
}

// ============================ fill variants ================================

// atomic-free fill: slot = rowstart[dst] + rank[e]; one 16B scattered store
__global__ void k_fillR(const int* __restrict__ dst, const int* __restrict__ src,
                        const float* __restrict__ ea, const int* __restrict__ rank,
                        const int* __restrict__ rowstart,
                        int4* __restrict__ payload, int nE) {
    int e = blockIdx.x * blockDim.x + threadIdx.x;
    if (e < nE) {
        float2 eav = ((const float2*)ea)[e];   // coalesced 8B
        int d = dst[e];                        // coalesced 4B
        int slot = rowstart[d] + rank[e];      // L2-resident probe + coalesced
        int4 p;
        p.x = __float_as_int(eav.x);
        p.y = __float_as_int(eav.y);
        p.z = src[e];
        p.w = 0;
        payload[slot] = p;                     // one 16B store
    }
}

// R5 fallback: atomic cursor fill
__global__ void k_fillP(const int* __restrict__ dst, const int* __restrict__ src,
                        const float* __restrict__ ea, int* __restrict__ cursor,
                        int4* __restrict__ payload, int nE) {
    int e = blockIdx.x * blockDim.x + threadIdx.x;
    if (e < nE) {
        float2 eav = ((const float2*)ea)[e];
        int sn = src[e];
        int slot = atomicAdd(&cursor[dst[e]], 1);
        int4 p;
        p.x = __float_as_int(eav.x);
        p.y = __float_as_int(eav.y);
        p.z = sn;
        p.w = 0;
        payload[slot] = p;
    }
}

// ============================ aggregation ==================================

// 16 threads/node; payload read sequentially (16B broadcast per group-step)
__global__ void k_aggP1(const int4* __restrict__ payload,
                        const int* __restrict__ rowstart,
                        const float* __restrict__ We, const float* __restrict__ be,
                        float* __restrict__ eagg, float* __restrict__ easum,
                        int nN) {
    __shared__ float w[48];   // [0..15]=We row0, [16..31]=We row1, [32..47]=be
    if (threadIdx.x < 32) w[threadIdx.x] = We[threadIdx.x];
    else if (threadIdx.x < 48) w[threadIdx.x] = be[threadIdx.x - 32];
    __syncthreads();
    int gid = blockIdx.x * blockDim.x + threadIdx.x;
    int v = gid >> 4, j = gid & 15;
    if (v >= nN) return;
    int s0 = rowstart[v], s1 = rowstart[v + 1];
    float acc = 0.f, aE = 0.f;
    for (int s = s0; s < s1; ++s) {
        int4 p = payload[s];
        float ea0 = __int_as_float(p.x), ea1 = __int_as_float(p.y);
        acc += fmaxf(fmaf(ea0, w[j], fmaf(ea1, w[16 + j], w[32 + j])), 0.f);
        if (j == 0) aE += ea0;
        else if (j == 1) aE += ea1;
    }
    eagg[v * 16 + j] = acc;
    if (j == 0) easum[2 * v] = aE;
    else if (j == 1) easum[2 * v + 1] = aE;
}

// 16 threads/node; sequential src + one coalesced 64B eagg line per edge
__global__ void k_aggP2(const int4* __restrict__ payload,
                        const int* __restrict__ rowstart,
                        const float* __restrict__ eagg, float* __restrict__ h2,
                        int nN) {
    int gid = blockIdx.x * blockDim.x + threadIdx.x;
    int v = gid >> 4, j = gid & 15;
    if (v >= nN) return;
    int s0 = rowstart[v], s1 = rowstart[v + 1];
    float acc = 0.f;
    for (int s = s0; s < s1; ++s) {
        int sn = payload[s].z;                 // sequential (stride 16B)
        acc += eagg[sn * 16 + j];              // 64B line per 16-lane group
    }
    h2[v * 16 + j] = acc;
}

// ========================= atomic tier (fallback) ==========================

__global__ void k_edge1(const float* __restrict__ ea, const int* __restrict__ dst,
                        const float* __restrict__ We, const float* __restrict__ be,
                        float* __restrict__ deg, float* __restrict__ easum,
                        float* __restrict__ eagg, int nE) {
    __shared__ float w[48];
    if (threadIdx.x < 32) w[threadIdx.x] = We[threadIdx.x];
    else if (threadIdx.x < 48) w[threadIdx.x] = be[threadIdx.x - 32];
    __syncthreads();
    const float2* ea2 = (const float2*)ea;
    long long stride = (long long)gridDim.x * blockDim.x;
    for (long long gid = (long long)blockIdx.x * blockDim.x + threadIdx.x;
         gid < 16LL * nE; gid += stride) {
        int e = (int)(gid >> 4);
        int j = (int)(gid & 15);
        int d = dst[e];
        float2 eav = ea2[e];
        float h = fmaxf(fmaf(eav.x, w[j], fmaf(eav.y, w[16 + j], w[32 + j])), 0.f);
        atomicAdd(&eagg[d * 16 + j], h);
        if (j == 0)      atomicAdd(&deg[d], 1.0f);
        else if (j == 1) atomicAdd(&easum[2 * d], eav.x);
        else if (j == 2) atomicAdd(&easum[2 * d + 1], eav.y);
    }
}

__global__ void k_edge2(const int* __restrict__ src, const int* __restrict__ dst,
                        const float* __restrict__ eagg, float* __restrict__ h2,
                        int nE) {
    long long stride = (long long)gridDim.x * blockDim.x;
    for (long long gid = (long long)blockIdx.x * blockDim.x + threadIdx.x;
         gid < 16LL * nE; gid += stride) {
        int e = (int)(gid >> 4);
        int j = (int)(gid & 15);
        atomicAdd(&h2[dst[e] * 16 + j], eagg[src[e] * 16 + j]);
    }
}

// ======================= fused node kernel (A+B) ===========================
// femb never materialized: each block of femb folds straight into acc[64].
template <bool DEG_FROM_CSR>
__global__ __launch_bounds__(256) void k_nodeAB(
    const float* __restrict__ x,
    const float* __restrict__ W_ego, const float* __restrict__ b_ego,
    const float* __restrict__ W_peer, const float* __restrict__ b_peer,
    const float* __restrict__ degf, const int* __restrict__ rowstart,
    const float* __restrict__ easum,
    const float* __restrict__ eagg, const float* __restrict__ h2,
    const float* __restrict__ W_emb, const float* __restrict__ b_emb,
    const float* __restrict__ bn_g, const float* __restrict__ bn_b,
    const float* __restrict__ bn_m, const float* __restrict__ bn_v,
    const float* __restrict__ W0, const float* __restrict__ b0,
    const float* __restrict__ W1, const float* __restrict__ b1,
    float* __restrict__ out, int nN) {
    __shared__ __align__(16) float sWe[64 * 32];   // W_ego [k][32]
    __shared__ __align__(16) float sWp[64 * 48];   // W_peer rows 0..63 (x part)
    __shared__ __align__(16) float sW[112 * 64];   // W_emb [k][64]
    __shared__ float sWpe[96];                     // W_peer rows 64,65
    __shared__ float sbe[32], sbp[48];
    __shared__ float sbias[64], sScale[64], sShift[64], sW0[64], sW1[64];

    for (int i = threadIdx.x; i < 64 * 32; i += 256) sWe[i] = W_ego[i];
    for (int i = threadIdx.x; i < 64 * 48; i += 256) sWp[i] = W_peer[i];
    for (int i = threadIdx.x; i < 112 * 64; i += 256) sW[i] = W_emb[i];
    if (threadIdx.x < 96) sWpe[threadIdx.x] = W_peer[64 * 48 + threadIdx.x];
    if (threadIdx.x < 32) sbe[threadIdx.x] = b_ego[threadIdx.x];
    if (threadIdx.x < 48) sbp[threadIdx.x] = b_peer[threadIdx.x];
    if (threadIdx.x < 64) {
        int j = threadIdx.x;
        sbias[j] = b_emb[j];
        float rstd = 1.0f / sqrtf(bn_v[j] + 1e-5f);
        float sc = bn_g[j] * rstd;
        sScale[j] = sc;
        sShift[j] = bn_b[j] - bn_m[j] * sc;
        sW0[j] = W0[j];
        sW1[j] = W1[j];
    }
    __syncthreads();

    int v = blockIdx.x * 256 + threadIdx.x;
    if (v >= nN) return;

    // ---- phase 1: accE = x@W_ego, accP = x@W_px ----
    float accE[32];
    float accP[48];
#pragma unroll
    for (int j = 0; j < 32; ++j) accE[j] = 0.f;
#pragma unroll
    for (int j = 0; j < 48; ++j) accP[j] = 0.f;

    const float4* x4 = (const float4*)(x + (long long)v * 64);
#pragma unroll 4
    for (int k4 = 0; k4 < 16; ++k4) {
        float4 xv = x4[k4];
        float xs[4] = {xv.x, xv.y, xv.z, xv.w};
#pragma unroll
        for (int t = 0; t < 4; ++t) {
            int k = 4 * k4 + t;
            float xk = xs[t];
            const float4* we4 = (const float4*)&sWe[k * 32];
#pragma unroll
            for (int j4 = 0; j4 < 8; ++j4) {
                float4 w = we4[j4];
                accE[4 * j4 + 0] = fmaf(xk, w.x, accE[4 * j4 + 0]);
                accE[4 * j4 + 1] = fmaf(xk, w.y, accE[4 * j4 + 1]);
                accE[4 * j4 + 2] = fmaf(xk, w.z, accE[4 * j4 + 2]);
                accE[4 * j4 + 3] = fmaf(xk, w.w, accE[4 * j4 + 3]);
            }
            const float4* wp4 = (const float4*)&sWp[k * 48];
#pragma unroll
            for (int j4 = 0; j4 < 12; ++j4) {
                float4 w = wp4[j4];
                accP[4 * j4 + 0] = fmaf(xk, w.x, accP[4 * j4 + 0]);
                accP[4 * j4 + 1] = fmaf(xk, w.y, accP[4 * j4 + 1]);
                accP[4 * j4 + 2] = fmaf(xk, w.z, accP[4 * j4 + 2]);
                accP[4 * j4 + 3] = fmaf(xk, w.w, accP[4 * j4 + 3]);
            }
        }
    }

    float dg;
    if (DEG_FROM_CSR) dg = (float)(rowstart[v + 1] - rowstart[v]);
    else              dg = degf[v];
    float dinv = dg > 0.f ? 1.0f / sqrtf(dg) : 0.f;
    float ea0 = easum[2 * v], ea1 = easum[2 * v + 1];

    // ---- phase 2: acc64 = b_emb + femb @ W_emb (femb folded in-register) ----
    float acc[64];
#pragma unroll
    for (int j = 0; j < 64; ++j) acc[j] = sbias[j];

    // helper macro: fold scalar f against W_emb row k
#define FOLD_ROW(kk, ff)                                            \
    {                                                               \
        const float4* wr4 = (const float4*)&sW[(kk) * 64];          \
        float fv_ = (ff);                                           \
        _Pragma("unroll")                                           \
        for (int j4 = 0; j4 < 16; ++j4) {                           \
            float4 w = wr4[j4];                                     \
            acc[4 * j4 + 0] = fmaf(fv_, w.x, acc[4 * j4 + 0]);      \
            acc[4 * j4 + 1] = fmaf(fv_, w.y, acc[4 * j4 + 1]);      \
            acc[4 * j4 + 2] = fmaf(fv_, w.z, acc[4 * j4 + 2]);      \
            acc[4 * j4 + 3] = fmaf(fv_, w.w, acc[4 * j4 + 3]);      \
        }                                                           \
    }

    // rows 0..31: h_ego = relu(accE + b_ego)
#pragma unroll
    for (int k = 0; k < 32; ++k) FOLD_ROW(k, fmaxf(accE[k] + sbe[k], 0.f));

    // rows 32..47: eagg
    {
        const float4* eg4 = (const float4*)(eagg + (long long)v * 16);
#pragma unroll
        for (int k4 = 0; k4 < 4; ++k4) {
            float4 g = eg4[k4];
            float gs[4] = {g.x, g.y, g.z, g.w};
#pragma unroll
            for (int t = 0; t < 4; ++t) FOLD_ROW(32 + 4 * k4 + t, gs[t]);
        }
    }

    // rows 48..63: dinv * h2
    {
        const float4* hh4 = (const float4*)(h2 + (long long)v * 16);
#pragma unroll
        for (int k4 = 0; k4 < 4; ++k4) {
            float4 g = hh4[k4];
            float gs[4] = {g.x, g.y, g.z, g.w};
#pragma unroll
            for (int t = 0; t < 4; ++t) FOLD_ROW(48 + 4 * k4 + t, dinv * gs[t]);
        }
    }

    // rows 64..111: h_peer = relu(dinv*(dg*(accP+b) + easum@W_pe))
#pragma unroll
    for (int k = 0; k < 48; ++k) {
        float t = dg * (accP[k] + sbp[k]) + fmaf(ea0, sWpe[k], ea1 * sWpe[48 + k]);
        FOLD_ROW(64 + k, fmaxf(dinv * t, 0.f));
    }
#undef FOLD_ROW

    // ---- epilogue: relu -> BN -> tanh -> heads ----
    float y0 = 0.f, y1 = 0.f;
#pragma unroll
    for (int j = 0; j < 64; ++j) {
        float e = fmaxf(acc[j], 0.f);
        e = fmaf(e, sScale[j], sShift[j]);
        e = tanhf(e);
        acc[j] = e;
        y0 = fmaf(e, sW0[j], y0);
        y1 = fmaf(e, sW1[j], y1);
    }

    float4* o4 = (float4*)(out + 2LL * nN + (long long)v * 64);
#pragma unroll
    for (int j4 = 0; j4 < 16; ++j4)
        o4[j4] = make_float4(acc[4 * j4], acc[4 * j4 + 1], acc[4 * j4 + 2], acc[4 * j4 + 3]);
    out[v] = y0 + b0[0];
    out[nN + v] = y1 + b1[0];
}

// ================================ launch ===================================

extern "C" void kernel_launch(void* const* d_in, const int* in_sizes, int n_in,
                              void* d_out, int out_size, void* d_ws, size_t ws_size,
                              hipStream_t stream) {
    const float* x      = (const float*)d_in[0];
    const float* ea     = (const float*)d_in[1];
    const int*   src    = (const int*)d_in[3];
    const int*   dst    = (const int*)d_in[4];
    const float* W_peer = (const float*)d_in[5];
    const float* b_peer = (const float*)d_in[6];
    const float* W_ego  = (const float*)d_in[7];
    const float* b_ego  = (const float*)d_in[8];
    const float* W_edge = (const float*)d_in[9];
    const float* b_edge = (const float*)d_in[10];
    const float* W_emb  = (const float*)d_in[11];
    const float* b_emb  = (const float*)d_in[12];
    const float* bn_g   = (const float*)d_in[13];
    const float* bn_b   = (const float*)d_in[14];
    const float* bn_m   = (const float*)d_in[15];
    const float* bn_v   = (const float*)d_in[16];
    const float* W0     = (const float*)d_in[17];
    const float* b0     = (const float*)d_in[18];
    const float* W1     = (const float*)d_in[19];
    const float* b1     = (const float*)d_in[20];

    int nE = in_sizes[3];
    int nN = in_sizes[2];

    int nBlocks  = (nN + 255) / 256;          // node kernel
    int ngBlocks = (16 * nN + 255) / 256;     // 16-thread-per-node kernels
    int eBlocks1 = (nE + 255) / 256;          // 1-thread-per-edge kernels

    // tier 1 (rank) element budget (4B units)
    size_t pre1   = (size_t)2 * nN + 4 + (size_t)nE;      // counts|rowstart|rank
    size_t pre1Al = (pre1 + 3) & ~(size_t)3;              // 16B-align payload
    size_t t1El   = pre1Al + 4ULL * nE + 34ULL * nN;      // +payload|eagg|easum|h2
    // tier 2 (cursor) budget
    size_t pre2   = (size_t)3 * nN + 4;
    size_t pre2Al = (pre2 + 3) & ~(size_t)3;
    size_t t2El   = pre2Al + 4ULL * nE + 34ULL * nN;

    if (ws_size >= 4 * t1El) {
        // ---------------- tier 1: rank-based, atomic-free fill ----------------
        int*   wsi      = (int*)d_ws;
        int*   counts   = wsi;                        // N
        int*   rowstart = wsi + nN;                   // N+1 (pad to N+4)
        int*   rank     = wsi + 2 * nN + 4;           // E
        int4*  payload  = (int4*)(wsi + pre1Al);      // E x 16B
        float* eagg     = (float*)(wsi + pre1Al + 4ULL * nE);  // 16N
        float* easum    = eagg + 16LL * nN;           // 2N
        float* h2       = easum + 2LL * nN;           // 16N

        hipMemsetAsync(counts, 0, sizeof(int) * (size_t)nN, stream);
        k_countR<<<eBlocks1, 256, 0, stream>>>(dst, counts, rank, nE);
        k_scan<false><<<1, 1024, 0, stream>>>(counts, rowstart, nullptr, nN, nE);
        k_fillR<<<eBlocks1, 256, 0, stream>>>(dst, src, ea, rank, rowstart,
                                              payload, nE);
        k_aggP1<<<ngBlocks, 256, 0, stream>>>(payload, rowstart, W_edge, b_edge,
                                              eagg, easum, nN);
        k_aggP2<<<ngBlocks, 256, 0, stream>>>(payload, rowstart, eagg, h2, nN);
        k_nodeAB<true><<<nBlocks, 256, 0, stream>>>(
            x, W_ego, b_ego, W_peer, b_peer, nullptr, rowstart, easum, eagg, h2,
            W_emb, b_emb, bn_g, bn_b, bn_m, bn_v, W0, b0, W1, b1,
            (float*)d_out, nN);
    } else if (ws_size >= 4 * t2El) {
        // ---------------- tier 2: cursor + atomic fill (R5) ----------------
        int*   wsi      = (int*)d_ws;
        int*   counts   = wsi;
        int*   rowstart = wsi + nN;
        int*   cursor   = wsi + 2 * nN + 4;
        int4*  payload  = (int4*)(wsi + pre2Al);
        float* eagg     = (float*)(wsi + pre2Al + 4ULL * nE);
        float* easum    = eagg + 16LL * nN;
        float* h2       = easum + 2LL * nN;

        hipMemsetAsync(counts, 0, sizeof(int) * (size_t)nN, stream);
        k_count<<<eBlocks1, 256, 0, stream>>>(dst, counts, nE);
        k_scan<true><<<1, 1024, 0, stream>>>(counts, rowstart, cursor, nN, nE);
        k_fillP<<<eBlocks1, 256, 0, stream>>>(dst, src, ea, cursor, payload, nE);
        k_aggP1<<<ngBlocks, 256, 0, stream>>>(payload, rowstart, W_edge, b_edge,
                                              eagg, easum, nN);
        k_aggP2<<<ngBlocks, 256, 0, stream>>>(payload, rowstart, eagg, h2, nN);
        k_nodeAB<true><<<nBlocks, 256, 0, stream>>>(
            x, W_ego, b_ego, W_peer, b_peer, nullptr, rowstart, easum, eagg, h2,
            W_emb, b_emb, bn_g, bn_b, bn_m, bn_v, W0, b0, W1, b1,
            (float*)d_out, nN);
    } else {
        // ---------------- tier 3: pure-atomic edges ----------------
        float* wsf   = (float*)d_ws;
        float* deg   = wsf;                  // N
        float* easum = wsf + nN;             // 2N
        float* eagg  = wsf + 3LL * nN;       // 16N
        float* h2    = wsf + 19LL * nN;      // 16N

        hipMemsetAsync(wsf, 0, sizeof(float) * 35ULL * nN, stream);
        const int eBlocks = 2048;
        k_edge1<<<eBlocks, 256, 0, stream>>>(ea, dst, W_edge, b_edge, deg, easum,
                                             eagg, nE);
        k_edge2<<<eBlocks, 256, 0, stream>>>(src, dst, eagg, h2, nE);
        k_nodeAB<false><<<nBlocks, 256, 0, stream>>>(
            x, W_ego, b_ego, W_peer, b_peer, deg, nullptr, easum, eagg, h2,
            W_emb, b_emb, bn_g, bn_b, bn_m, bn_v, W0, b0, W1, b1,
            (float*)d_out, nN);
    }
}

// Round 11
// 427.955 us; speedup vs baseline: 7.3409x; 7.3409x over previous
//
#include <hip/hip_runtime.h>
#include <math.h>

// ---------------------------------------------------------------------------
// GNN TLearner forward, MI355X.
// R10 = R8 resubmitted (R9/R10 benches were infra failures; fix unvalidated).
// R8: fix R7's overlay off-by-N. Fixed-region sizes were understated by N
//     (tier1: 36N+4 not 35N+4; tier2: 37N+4 not 36N+4), so femb overlapped
//     h2's tail -> cross-block race -> absmax 0.687. Offsets corrected; no
//     other changes vs R7 (split node kernels + rank fill + float4 LDS reads).
//
// Algebra (audited R3): peer MLP folded to node level; 2-hop deg_inv factored;
// relu(f_emb) dropped (all components >=0); deg = rowstart[v+1]-rowstart[v].
//
// Tier 1: memset(counts) -> k_countR -> k_scan -> k_fillR
//         -> k_aggP1 -> k_aggP2 -> k_nodeA -> k_nodeB
// Tier 2: cursor+atomic fill (R5). Tier 3: pure-atomic edges.
//
// Tier1 ws (4B elems):
//   counts[N] | rowstart[N+4] | eagg[16N] | easum[2N] | h2[16N]   (= 36N+4)
//   then REGION{ rank[E] | payload[4E] } overlaid later by femb[112N]
// out layout (floats): y0[N] | y1[N] | emb[64N]
// ---------------------------------------------------------------------------

// ============================ CSR-build kernels ============================

__global__ void k_countR(const int* __restrict__ dst, int* __restrict__ counts,
                         int* __restrict__ rank, int nE) {
    int e = blockIdx.x * blockDim.x + threadIdx.x;
    if (e < nE) rank[e] = atomicAdd(&counts[dst[e]], 1);
}

__global__ void k_count(const int* __restrict__ dst, int* __restrict__ counts,
                        int nE) {
    int e = blockIdx.x * blockDim.x + threadIdx.x;
    if (e < nE) atomicAdd(&counts[dst[e]], 1);
}

template <bool WRITE_CURSOR>
__global__ __launch_bounds__(1024) void k_scan(const int* __restrict__ counts,
                                               int* __restrict__ rowstart,
                                               int* __restrict__ cursor,
                                               int nN, int nE) {
    __shared__ int s[1024];
    int t = threadIdx.x;
    int C = (nN + 1023) / 1024;
    int lo = min(t * C, nN), hi = min(lo + C, nN);
    int sum = 0;
    for (int i = lo; i < hi; ++i) sum += counts[i];
    s[t] = sum;
    __syncthreads();
    for (int off = 1; off < 1024; off <<= 1) {
        int v = (t >= off) ? s[t - off] : 0;
        __syncthreads();
        s[t] += v;
        __syncthreads();
    }
    int run = (t == 0) ? 0 : s[t - 1];
    for (int i = lo; i < hi; ++i) {
        rowstart[i] = run;
        if (WRITE_CURSOR) cursor[i] = run;
        run += counts[i];
    }
    if (t == 0) rowstart[nN] = nE;
}

// ============================ fill variants ================================

// atomic-free fill: slot = rowstart[dst] + rank[e]; one 16B scattered store
__global__ void k_fillR(const int* __restrict__ dst, const int* __restrict__ src,
                        const float* __restrict__ ea, const int* __restrict__ rank,
                        const int* __restrict__ rowstart,
                        int4* __restrict__ payload, int nE) {
    int e = blockIdx.x * blockDim.x + threadIdx.x;
    if (e < nE) {
        float2 eav = ((const float2*)ea)[e];   // coalesced 8B
        int d = dst[e];                        // coalesced 4B
        int slot = rowstart[d] + rank[e];      // L2 probe + coalesced
        int4 p;
        p.x = __float_as_int(eav.x);
        p.y = __float_as_int(eav.y);
        p.z = src[e];
        p.w = 0;
        payload[slot] = p;                     // one 16B store (fire-and-forget)
    }
}

__global__ void k_fillP(const int* __restrict__ dst, const int* __restrict__ src,
                        const float* __restrict__ ea, int* __restrict__ cursor,
                        int4* __restrict__ payload, int nE) {
    int e = blockIdx.x * blockDim.x + threadIdx.x;
    if (e < nE) {
        float2 eav = ((const float2*)ea)[e];
        int sn = src[e];
        int slot = atomicAdd(&cursor[dst[e]], 1);
        int4 p;
        p.x = __float_as_int(eav.x);
        p.y = __float_as_int(eav.y);
        p.z = sn;
        p.w = 0;
        payload[slot] = p;
    }
}

// ============================ aggregation ==================================

// 16 threads/node; payload read sequentially (16B broadcast per group-step)
__global__ void k_aggP1(const int4* __restrict__ payload,
                        const int* __restrict__ rowstart,
                        const float* __restrict__ We, const float* __restrict__ be,
                        float* __restrict__ eagg, float* __restrict__ easum,
                        int nN) {
    __shared__ float w[48];   // [0..15]=We row0, [16..31]=We row1, [32..47]=be
    if (threadIdx.x < 32) w[threadIdx.x] = We[threadIdx.x];
    else if (threadIdx.x < 48) w[threadIdx.x] = be[threadIdx.x - 32];
    __syncthreads();
    int gid = blockIdx.x * blockDim.x + threadIdx.x;
    int v = gid >> 4, j = gid & 15;
    if (v >= nN) return;
    int s0 = rowstart[v], s1 = rowstart[v + 1];
    float acc = 0.f, aE = 0.f;
    for (int s = s0; s < s1; ++s) {
        int4 p = payload[s];
        float ea0 = __int_as_float(p.x), ea1 = __int_as_float(p.y);
        acc += fmaxf(fmaf(ea0, w[j], fmaf(ea1, w[16 + j], w[32 + j])), 0.f);
        if (j == 0) aE += ea0;
        else if (j == 1) aE += ea1;
    }
    eagg[v * 16 + j] = acc;
    if (j == 0) easum[2 * v] = aE;
    else if (j == 1) easum[2 * v + 1] = aE;
}

// 16 threads/node; sequential src + one coalesced 64B eagg line per edge
__global__ void k_aggP2(const int4* __restrict__ payload,
                        const int* __restrict__ rowstart,
                        const float* __restrict__ eagg, float* __restrict__ h2,
                        int nN) {
    int gid = blockIdx.x * blockDim.x + threadIdx.x;
    int v = gid >> 4, j = gid & 15;
    if (v >= nN) return;
    int s0 = rowstart[v], s1 = rowstart[v + 1];
    float acc = 0.f;
    for (int s = s0; s < s1; ++s) {
        int sn = payload[s].z;                 // sequential (stride 16B)
        acc += eagg[sn * 16 + j];              // 64B line per 16-lane group
    }
    h2[v * 16 + j] = acc;
}

// ========================= atomic tier (fallback) ==========================

__global__ void k_edge1(const float* __restrict__ ea, const int* __restrict__ dst,
                        const float* __restrict__ We, const float* __restrict__ be,
                        float* __restrict__ deg, float* __restrict__ easum,
                        float* __restrict__ eagg, int nE) {
    __shared__ float w[48];
    if (threadIdx.x < 32) w[threadIdx.x] = We[threadIdx.x];
    else if (threadIdx.x < 48) w[threadIdx.x] = be[threadIdx.x - 32];
    __syncthreads();
    const float2* ea2 = (const float2*)ea;
    long long stride = (long long)gridDim.x * blockDim.x;
    for (long long gid = (long long)blockIdx.x * blockDim.x + threadIdx.x;
         gid < 16LL * nE; gid += stride) {
        int e = (int)(gid >> 4);
        int j = (int)(gid & 15);
        int d = dst[e];
        float2 eav = ea2[e];
        float h = fmaxf(fmaf(eav.x, w[j], fmaf(eav.y, w[16 + j], w[32 + j])), 0.f);
        atomicAdd(&eagg[d * 16 + j], h);
        if (j == 0)      atomicAdd(&deg[d], 1.0f);
        else if (j == 1) atomicAdd(&easum[2 * d], eav.x);
        else if (j == 2) atomicAdd(&easum[2 * d + 1], eav.y);
    }
}

__global__ void k_edge2(const int* __restrict__ src, const int* __restrict__ dst,
                        const float* __restrict__ eagg, float* __restrict__ h2,
                        int nE) {
    long long stride = (long long)gridDim.x * blockDim.x;
    for (long long gid = (long long)blockIdx.x * blockDim.x + threadIdx.x;
         gid < 16LL * nE; gid += stride) {
        int e = (int)(gid >> 4);
        int j = (int)(gid & 15);
        atomicAdd(&h2[dst[e] * 16 + j], eagg[src[e] * 16 + j]);
    }
}

// ============================= node kernels ================================

template <bool DEG_FROM_CSR>
__global__ __launch_bounds__(256) void k_nodeA(
    const float* __restrict__ x,
    const float* __restrict__ W_ego, const float* __restrict__ b_ego,
    const float* __restrict__ W_peer, const float* __restrict__ b_peer,
    const float* __restrict__ degf, const int* __restrict__ rowstart,
    const float* __restrict__ easum,
    const float* __restrict__ eagg, const float* __restrict__ h2,
    float* __restrict__ femb, int nN) {
    __shared__ __align__(16) float sWe[64 * 32];   // W_ego [k][32]
    __shared__ __align__(16) float sWp[64 * 48];   // W_peer rows 0..63 (x part)
    __shared__ float sWpe[96];                     // W_peer rows 64,65
    __shared__ float sbe[32];
    __shared__ float sbp[48];
    for (int i = threadIdx.x; i < 64 * 32; i += 256) sWe[i] = W_ego[i];
    for (int i = threadIdx.x; i < 64 * 48; i += 256) sWp[i] = W_peer[i];
    if (threadIdx.x < 96) sWpe[threadIdx.x] = W_peer[64 * 48 + threadIdx.x];
    if (threadIdx.x < 32) sbe[threadIdx.x] = b_ego[threadIdx.x];
    if (threadIdx.x < 48) sbp[threadIdx.x] = b_peer[threadIdx.x];
    __syncthreads();

    int v = blockIdx.x * 256 + threadIdx.x;
    if (v >= nN) return;

    float accE[32];
    float accP[48];
#pragma unroll
    for (int j = 0; j < 32; ++j) accE[j] = 0.f;
#pragma unroll
    for (int j = 0; j < 48; ++j) accP[j] = 0.f;

    const float4* x4 = (const float4*)(x + (long long)v * 64);
#pragma unroll 4
    for (int k4 = 0; k4 < 16; ++k4) {
        float4 xv = x4[k4];
        float xs[4] = {xv.x, xv.y, xv.z, xv.w};
#pragma unroll
        for (int t = 0; t < 4; ++t) {
            int k = 4 * k4 + t;
            float xk = xs[t];
            const float4* we4 = (const float4*)&sWe[k * 32];
#pragma unroll
            for (int j4 = 0; j4 < 8; ++j4) {
                float4 w = we4[j4];
                accE[4 * j4 + 0] = fmaf(xk, w.x, accE[4 * j4 + 0]);
                accE[4 * j4 + 1] = fmaf(xk, w.y, accE[4 * j4 + 1]);
                accE[4 * j4 + 2] = fmaf(xk, w.z, accE[4 * j4 + 2]);
                accE[4 * j4 + 3] = fmaf(xk, w.w, accE[4 * j4 + 3]);
            }
            const float4* wp4 = (const float4*)&sWp[k * 48];
#pragma unroll
            for (int j4 = 0; j4 < 12; ++j4) {
                float4 w = wp4[j4];
                accP[4 * j4 + 0] = fmaf(xk, w.x, accP[4 * j4 + 0]);
                accP[4 * j4 + 1] = fmaf(xk, w.y, accP[4 * j4 + 1]);
                accP[4 * j4 + 2] = fmaf(xk, w.z, accP[4 * j4 + 2]);
                accP[4 * j4 + 3] = fmaf(xk, w.w, accP[4 * j4 + 3]);
            }
        }
    }

    float dg;
    if (DEG_FROM_CSR) dg = (float)(rowstart[v + 1] - rowstart[v]);
    else              dg = degf[v];
    float dinv = dg > 0.f ? 1.0f / sqrtf(dg) : 0.f;
    float ea0 = easum[2 * v], ea1 = easum[2 * v + 1];

    float* fo = femb + (long long)v * 112;
#pragma unroll
    for (int j = 0; j < 32; ++j) fo[j] = fmaxf(accE[j] + sbe[j], 0.f);
#pragma unroll
    for (int j = 0; j < 16; ++j) fo[32 + j] = eagg[v * 16 + j];
#pragma unroll
    for (int j = 0; j < 16; ++j) fo[48 + j] = dinv * h2[v * 16 + j];
#pragma unroll
    for (int j = 0; j < 48; ++j) {
        float t = dg * (accP[j] + sbp[j]) + fmaf(ea0, sWpe[j], ea1 * sWpe[48 + j]);
        fo[64 + j] = fmaxf(dinv * t, 0.f);
    }
}

__global__ __launch_bounds__(256) void k_nodeB(
    const float* __restrict__ femb,
    const float* __restrict__ W_emb, const float* __restrict__ b_emb,
    const float* __restrict__ bn_g, const float* __restrict__ bn_b,
    const float* __restrict__ bn_m, const float* __restrict__ bn_v,
    const float* __restrict__ W0, const float* __restrict__ b0,
    const float* __restrict__ W1, const float* __restrict__ b1,
    float* __restrict__ out, int nN) {
    __shared__ __align__(16) float sW[112 * 64];   // W_emb [k][64]
    __shared__ float sbias[64], sScale[64], sShift[64], sW0[64], sW1[64];
    for (int i = threadIdx.x; i < 112 * 64; i += 256) sW[i] = W_emb[i];
    if (threadIdx.x < 64) {
        int j = threadIdx.x;
        sbias[j] = b_emb[j];
        float rstd = 1.0f / sqrtf(bn_v[j] + 1e-5f);
        float sc = bn_g[j] * rstd;
        sScale[j] = sc;
        sShift[j] = bn_b[j] - bn_m[j] * sc;
        sW0[j] = W0[j];
        sW1[j] = W1[j];
    }
    __syncthreads();

    int v = blockIdx.x * 256 + threadIdx.x;
    if (v >= nN) return;

    float acc[64];
#pragma unroll
    for (int j = 0; j < 64; ++j) acc[j] = 0.f;

    const float4* f4 = (const float4*)(femb + (long long)v * 112);
#pragma unroll 4
    for (int k4 = 0; k4 < 28; ++k4) {
        float4 fv = f4[k4];
        float fs[4] = {fv.x, fv.y, fv.z, fv.w};
#pragma unroll
        for (int t = 0; t < 4; ++t) {
            int k = 4 * k4 + t;
            float fk = fs[t];
            const float4* wr4 = (const float4*)&sW[k * 64];
#pragma unroll
            for (int j4 = 0; j4 < 16; ++j4) {
                float4 w = wr4[j4];
                acc[4 * j4 + 0] = fmaf(fk, w.x, acc[4 * j4 + 0]);
                acc[4 * j4 + 1] = fmaf(fk, w.y, acc[4 * j4 + 1]);
                acc[4 * j4 + 2] = fmaf(fk, w.z, acc[4 * j4 + 2]);
                acc[4 * j4 + 3] = fmaf(fk, w.w, acc[4 * j4 + 3]);
            }
        }
    }

    float y0 = 0.f, y1 = 0.f;
#pragma unroll
    for (int j = 0; j < 64; ++j) {
        float e = fmaxf(acc[j] + sbias[j], 0.f);
        e = fmaf(e, sScale[j], sShift[j]);   // BN inference affine
        e = tanhf(e);
        acc[j] = e;
        y0 = fmaf(e, sW0[j], y0);
        y1 = fmaf(e, sW1[j], y1);
    }

    float4* o4 = (float4*)(out + 2LL * nN + (long long)v * 64);
#pragma unroll
    for (int j4 = 0; j4 < 16; ++j4)
        o4[j4] = make_float4(acc[4 * j4], acc[4 * j4 + 1], acc[4 * j4 + 2], acc[4 * j4 + 3]);
    out[v] = y0 + b0[0];
    out[nN + v] = y1 + b1[0];
}

// ================================ launch ===================================

extern "C" void kernel_launch(void* const* d_in, const int* in_sizes, int n_in,
                              void* d_out, int out_size, void* d_ws, size_t ws_size,
                              hipStream_t stream) {
    const float* x      = (const float*)d_in[0];
    const float* ea     = (const float*)d_in[1];
    const int*   src    = (const int*)d_in[3];
    const int*   dst    = (const int*)d_in[4];
    const float* W_peer = (const float*)d_in[5];
    const float* b_peer = (const float*)d_in[6];
    const float* W_ego  = (const float*)d_in[7];
    const float* b_ego  = (const float*)d_in[8];
    const float* W_edge = (const float*)d_in[9];
    const float* b_edge = (const float*)d_in[10];
    const float* W_emb  = (const float*)d_in[11];
    const float* b_emb  = (const float*)d_in[12];
    const float* bn_g   = (const float*)d_in[13];
    const float* bn_b   = (const float*)d_in[14];
    const float* bn_m   = (const float*)d_in[15];
    const float* bn_v   = (const float*)d_in[16];
    const float* W0     = (const float*)d_in[17];
    const float* b0     = (const float*)d_in[18];
    const float* W1     = (const float*)d_in[19];
    const float* b1     = (const float*)d_in[20];

    int nE = in_sizes[3];
    int nN = in_sizes[2];

    int nBlocks  = (nN + 255) / 256;          // node kernels
    int ngBlocks = (16 * nN + 255) / 256;     // 16-thread-per-node kernels
    int eBlocks1 = (nE + 255) / 256;          // 1-thread-per-edge kernels

    // tier 1 fixed region: counts N | rowstart N+4 | eagg 16N | easum 2N |
    // h2 16N  = 36N+4 elems  (R7 BUG: had 35N+4 -> femb overlapped h2 tail)
    size_t fixed1   = (size_t)36 * nN + 4;
    size_t fixed1Al = (fixed1 + 3) & ~(size_t)3;
    size_t regElems = 5ULL * nE + 4;  // rank E + payload 4E (+align slop)
    size_t fembEl   = (size_t)112 * nN;
    size_t t1El     = fixed1Al + (regElems > fembEl ? regElems : fembEl);
    // tier 2 fixed region: counts N | rowstart N+4 | cursor N | eagg 16N |
    // easum 2N | h2 16N = 37N+4 elems  (R7 BUG: had 36N+4)
    size_t fixed2   = (size_t)37 * nN + 4;
    size_t fixed2Al = (fixed2 + 3) & ~(size_t)3;
    size_t reg2     = 4ULL * nE + 4;
    size_t t2El     = fixed2Al + (reg2 > fembEl ? reg2 : fembEl);

    if (ws_size >= 4 * t1El) {
        // ---------------- tier 1: rank-based, atomic-free fill ----------------
        int*   wsi      = (int*)d_ws;
        int*   counts   = wsi;                        // N
        int*   rowstart = wsi + nN;                   // N+1 (pad to N+4)
        float* eagg     = (float*)(wsi + 2 * nN + 4); // 16N   [2N+4 .. 18N+4)
        float* easum    = eagg + 16LL * nN;           // 2N    [18N+4 .. 20N+4)
        float* h2       = easum + 2LL * nN;           // 16N   [20N+4 .. 36N+4)
        int*   rank     = wsi + fixed1Al;             // E
        size_t payOff   = (fixed1Al + (size_t)nE + 3) & ~(size_t)3;
        int4*  payload  = (int4*)(wsi + payOff);      // E x 16B
        float* femb     = (float*)(wsi + fixed1Al);   // 112N (overlays rank/payload)

        hipMemsetAsync(counts, 0, sizeof(int) * (size_t)nN, stream);
        k_countR<<<eBlocks1, 256, 0, stream>>>(dst, counts, rank, nE);
        k_scan<false><<<1, 1024, 0, stream>>>(counts, rowstart, nullptr, nN, nE);
        k_fillR<<<eBlocks1, 256, 0, stream>>>(dst, src, ea, rank, rowstart,
                                              payload, nE);
        k_aggP1<<<ngBlocks, 256, 0, stream>>>(payload, rowstart, W_edge, b_edge,
                                              eagg, easum, nN);
        k_aggP2<<<ngBlocks, 256, 0, stream>>>(payload, rowstart, eagg, h2, nN);
        // payload/rank dead from here; femb overlays them (stream-ordered)
        k_nodeA<true><<<nBlocks, 256, 0, stream>>>(x, W_ego, b_ego, W_peer, b_peer,
                                                   nullptr, rowstart, easum,
                                                   eagg, h2, femb, nN);
        k_nodeB<<<nBlocks, 256, 0, stream>>>(femb, W_emb, b_emb, bn_g, bn_b, bn_m,
                                             bn_v, W0, b0, W1, b1, (float*)d_out, nN);
    } else if (ws_size >= 4 * t2El) {
        // ---------------- tier 2: cursor + atomic fill (R5) ----------------
        int*   wsi      = (int*)d_ws;
        int*   counts   = wsi;                        // N
        int*   rowstart = wsi + nN;                   // N+1 (pad to N+4)
        int*   cursor   = wsi + 2 * nN + 4;           // N
        float* eagg     = (float*)(wsi + 3 * nN + 4); // 16N   [3N+4 .. 19N+4)
        float* easum    = eagg + 16LL * nN;           // 2N    [19N+4 .. 21N+4)
        float* h2       = easum + 2LL * nN;           // 16N   [21N+4 .. 37N+4)
        int4*  payload  = (int4*)(wsi + fixed2Al);    // E x 16B
        float* femb     = (float*)(wsi + fixed2Al);   // overlays payload

        hipMemsetAsync(counts, 0, sizeof(int) * (size_t)nN, stream);
        k_count<<<eBlocks1, 256, 0, stream>>>(dst, counts, nE);
        k_scan<true><<<1, 1024, 0, stream>>>(counts, rowstart, cursor, nN, nE);
        k_fillP<<<eBlocks1, 256, 0, stream>>>(dst, src, ea, cursor, payload, nE);
        k_aggP1<<<ngBlocks, 256, 0, stream>>>(payload, rowstart, W_edge, b_edge,
                                              eagg, easum, nN);
        k_aggP2<<<ngBlocks, 256, 0, stream>>>(payload, rowstart, eagg, h2, nN);
        k_nodeA<true><<<nBlocks, 256, 0, stream>>>(x, W_ego, b_ego, W_peer, b_peer,
                                                   nullptr, rowstart, easum,
                                                   eagg, h2, femb, nN);
        k_nodeB<<<nBlocks, 256, 0, stream>>>(femb, W_emb, b_emb, bn_g, bn_b, bn_m,
                                             bn_v, W0, b0, W1, b1, (float*)d_out, nN);
    } else {
        // ---------------- tier 3: pure-atomic edges ----------------
        float* wsf   = (float*)d_ws;
        float* deg   = wsf;                  // N
        float* easum = wsf + nN;             // 2N
        float* eagg  = wsf + 3LL * nN;       // 16N
        float* h2    = wsf + 19LL * nN;      // 16N
        float* femb  = wsf + 35LL * nN;      // 112N

        hipMemsetAsync(wsf, 0, sizeof(float) * 35ULL * nN, stream);
        const int eBlocks = 2048;
        k_edge1<<<eBlocks, 256, 0, stream>>>(ea, dst, W_edge, b_edge, deg, easum,
                                             eagg, nE);
        k_edge2<<<eBlocks, 256, 0, stream>>>(src, dst, eagg, h2, nE);
        k_nodeA<false><<<nBlocks, 256, 0, stream>>>(x, W_ego, b_ego, W_peer, b_peer,
                                                    deg, nullptr, easum,
                                                    eagg, h2, femb, nN);
        k_nodeB<<<nBlocks, 256, 0, stream>>>(femb, W_emb, b_emb, bn_g, bn_b, bn_m,
                                             bn_v, W0, b0, W1, b1, (float*)d_out, nN);
    }
}

// Round 12
// 415.256 us; speedup vs baseline: 7.5654x; 1.0306x over previous
//
#include <hip/hip_runtime.h>
#include <math.h>

// ---------------------------------------------------------------------------
// GNN TLearner forward, MI355X.
// R11: node kernels re-parallelized. R8's counters: k_nodeB 90us with
//      Occupancy 8.4% / VALU 8.7% / HBM 3.5% -- 196-block grid on 256 CUs,
//      1 node/thread. Now 8 threads/node, 32 nodes/block -> 1563 blocks:
//      k_nodeB: femb+W in LDS, thread owns 8 channels, shfl-reduce y0/y1.
//      k_nodeA: x-tile+W in LDS, thread owns 4 ego + 6 peer channels.
// CSR build / agg kernels / tiers / ws layout unchanged from R8.
//
// Algebra (audited R3): peer MLP folded to node level; 2-hop deg_inv factored;
// relu(f_emb) dropped (all components >=0); deg = rowstart[v+1]-rowstart[v].
//
// Tier1 ws (4B elems):
//   counts[N] | rowstart[N+4] | eagg[16N] | easum[2N] | h2[16N]   (= 36N+4)
//   then REGION{ rank[E] | payload[4E] } overlaid later by femb[112N]
// out layout (floats): y0[N] | y1[N] | emb[64N]
// ---------------------------------------------------------------------------

// ============================ CSR-build kernels ============================

__global__ void k_countR(const int* __restrict__ dst, int* __restrict__ counts,
                         int* __restrict__ rank, int nE) {
    int e = blockIdx.x * blockDim.x + threadIdx.x;
    if (e < nE) rank[e] = atomicAdd(&counts[dst[e]], 1);
}

__global__ void k_count(const int* __restrict__ dst, int* __restrict__ counts,
                        int nE) {
    int e = blockIdx.x * blockDim.x + threadIdx.x;
    if (e < nE) atomicAdd(&counts[dst[e]], 1);
}

template <bool WRITE_CURSOR>
__global__ __launch_bounds__(1024) void k_scan(const int* __restrict__ counts,
                                               int* __restrict__ rowstart,
                                               int* __restrict__ cursor,
                                               int nN, int nE) {
    __shared__ int s[1024];
    int t = threadIdx.x;
    int C = (nN + 1023) / 1024;
    int lo = min(t * C, nN), hi = min(lo + C, nN);
    int sum = 0;
    for (int i = lo; i < hi; ++i) sum += counts[i];
    s[t] = sum;
    __syncthreads();
    for (int off = 1; off < 1024; off <<= 1) {
        int v = (t >= off) ? s[t - off] : 0;
        __syncthreads();
        s[t] += v;
        __syncthreads();
    }
    int run = (t == 0) ? 0 : s[t - 1];
    for (int i = lo; i < hi; ++i) {
        rowstart[i] = run;
        if (WRITE_CURSOR) cursor[i] = run;
        run += counts[i];
    }
    if (t == 0) rowstart[nN] = nE;
}

// ============================ fill variants ================================

__global__ void k_fillR(const int* __restrict__ dst, const int* __restrict__ src,
                        const float* __restrict__ ea, const int* __restrict__ rank,
                        const int* __restrict__ rowstart,
                        int4* __restrict__ payload, int nE) {
    int e = blockIdx.x * blockDim.x + threadIdx.x;
    if (e < nE) {
        float2 eav = ((const float2*)ea)[e];   // coalesced 8B
        int d = dst[e];                        // coalesced 4B
        int slot = rowstart[d] + rank[e];      // L2 probe + coalesced
        int4 p;
        p.x = __float_as_int(eav.x);
        p.y = __float_as_int(eav.y);
        p.z = src[e];
        p.w = 0;
        payload[slot] = p;                     // one 16B store (fire-and-forget)
    }
}

__global__ void k_fillP(const int* __restrict__ dst, const int* __restrict__ src,
                        const float* __restrict__ ea, int* __restrict__ cursor,
                        int4* __restrict__ payload, int nE) {
    int e = blockIdx.x * blockDim.x + threadIdx.x;
    if (e < nE) {
        float2 eav = ((const float2*)ea)[e];
        int sn = src[e];
        int slot = atomicAdd(&cursor[dst[e]], 1);
        int4 p;
        p.x = __float_as_int(eav.x);
        p.y = __float_as_int(eav.y);
        p.z = sn;
        p.w = 0;
        payload[slot] = p;
    }
}

// ============================ aggregation ==================================

__global__ void k_aggP1(const int4* __restrict__ payload,
                        const int* __restrict__ rowstart,
                        const float* __restrict__ We, const float* __restrict__ be,
                        float* __restrict__ eagg, float* __restrict__ easum,
                        int nN) {
    __shared__ float w[48];   // [0..15]=We row0, [16..31]=We row1, [32..47]=be
    if (threadIdx.x < 32) w[threadIdx.x] = We[threadIdx.x];
    else if (threadIdx.x < 48) w[threadIdx.x] = be[threadIdx.x - 32];
    __syncthreads();
    int gid = blockIdx.x * blockDim.x + threadIdx.x;
    int v = gid >> 4, j = gid & 15;
    if (v >= nN) return;
    int s0 = rowstart[v], s1 = rowstart[v + 1];
    float acc = 0.f, aE = 0.f;
    for (int s = s0; s < s1; ++s) {
        int4 p = payload[s];
        float ea0 = __int_as_float(p.x), ea1 = __int_as_float(p.y);
        acc += fmaxf(fmaf(ea0, w[j], fmaf(ea1, w[16 + j], w[32 + j])), 0.f);
        if (j == 0) aE += ea0;
        else if (j == 1) aE += ea1;
    }
    eagg[v * 16 + j] = acc;
    if (j == 0) easum[2 * v] = aE;
    else if (j == 1) easum[2 * v + 1] = aE;
}

__global__ void k_aggP2(const int4* __restrict__ payload,
                        const int* __restrict__ rowstart,
                        const float* __restrict__ eagg, float* __restrict__ h2,
                        int nN) {
    int gid = blockIdx.x * blockDim.x + threadIdx.x;
    int v = gid >> 4, j = gid & 15;
    if (v >= nN) return;
    int s0 = rowstart[v], s1 = rowstart[v + 1];
    float acc = 0.f;
    for (int s = s0; s < s1; ++s) {
        int sn = payload[s].z;                 // sequential (stride 16B)
        acc += eagg[sn * 16 + j];              // 64B line per 16-lane group
    }
    h2[v * 16 + j] = acc;
}

// ========================= atomic tier (fallback) ==========================

__global__ void k_edge1(const float* __restrict__ ea, const int* __restrict__ dst,
                        const float* __restrict__ We, const float* __restrict__ be,
                        float* __restrict__ deg, float* __restrict__ easum,
                        float* __restrict__ eagg, int nE) {
    __shared__ float w[48];
    if (threadIdx.x < 32) w[threadIdx.x] = We[threadIdx.x];
    else if (threadIdx.x < 48) w[threadIdx.x] = be[threadIdx.x - 32];
    __syncthreads();
    const float2* ea2 = (const float2*)ea;
    long long stride = (long long)gridDim.x * blockDim.x;
    for (long long gid = (long long)blockIdx.x * blockDim.x + threadIdx.x;
         gid < 16LL * nE; gid += stride) {
        int e = (int)(gid >> 4);
        int j = (int)(gid & 15);
        int d = dst[e];
        float2 eav = ea2[e];
        float h = fmaxf(fmaf(eav.x, w[j], fmaf(eav.y, w[16 + j], w[32 + j])), 0.f);
        atomicAdd(&eagg[d * 16 + j], h);
        if (j == 0)      atomicAdd(&deg[d], 1.0f);
        else if (j == 1) atomicAdd(&easum[2 * d], eav.x);
        else if (j == 2) atomicAdd(&easum[2 * d + 1], eav.y);
    }
}

__global__ void k_edge2(const int* __restrict__ src, const int* __restrict__ dst,
                        const float* __restrict__ eagg, float* __restrict__ h2,
                        int nE) {
    long long stride = (long long)gridDim.x * blockDim.x;
    for (long long gid = (long long)blockIdx.x * blockDim.x + threadIdx.x;
         gid < 16LL * nE; gid += stride) {
        int e = (int)(gid >> 4);
        int j = (int)(gid & 15);
        atomicAdd(&h2[dst[e] * 16 + j], eagg[src[e] * 16 + j]);
    }
}

// ============================= node kernels ================================
// 8 threads per node, 32 nodes per 256-thread block -> 1563 blocks @ N=50000.

template <bool DEG_FROM_CSR>
__global__ __launch_bounds__(256) void k_nodeA(
    const float* __restrict__ x,
    const float* __restrict__ W_ego, const float* __restrict__ b_ego,
    const float* __restrict__ W_peer, const float* __restrict__ b_peer,
    const float* __restrict__ degf, const int* __restrict__ rowstart,
    const float* __restrict__ easum,
    const float* __restrict__ eagg, const float* __restrict__ h2,
    float* __restrict__ femb, int nN) {
    __shared__ __align__(16) float sWe[64 * 32];   // W_ego [k][32]
    __shared__ __align__(16) float sWp[64 * 48];   // W_peer rows 0..63 (x part)
    __shared__ __align__(16) float sx[32 * 64];    // x tile (32 nodes)
    __shared__ float sWpe[96];                     // W_peer rows 64,65
    __shared__ float sbe[32];
    __shared__ float sbp[48];
    for (int i = threadIdx.x; i < 64 * 32; i += 256) sWe[i] = W_ego[i];
    for (int i = threadIdx.x; i < 64 * 48; i += 256) sWp[i] = W_peer[i];
    if (threadIdx.x < 96) sWpe[threadIdx.x] = W_peer[64 * 48 + threadIdx.x];
    if (threadIdx.x < 32) sbe[threadIdx.x] = b_ego[threadIdx.x];
    if (threadIdx.x < 48) sbp[threadIdx.x] = b_peer[threadIdx.x];

    long long base = (long long)blockIdx.x * 32;
    {
        int nv = (int)min(32LL, (long long)nN - base);
        if (nv > 0) {
            const float4* xs = (const float4*)(x + base * 64);
            int lim = nv * 16;   // 16 float4 per node
            for (int i = threadIdx.x; i < lim; i += 256)
                ((float4*)sx)[i] = xs[i];
        }
    }
    __syncthreads();

    int g = threadIdx.x >> 3;       // node group 0..31
    int t = threadIdx.x & 7;        // lane-in-group 0..7
    long long v = base + g;
    if (v >= nN) return;

    float accE[4] = {0.f, 0.f, 0.f, 0.f};
    float accP[6] = {0.f, 0.f, 0.f, 0.f, 0.f, 0.f};
    const float* xv = &sx[g * 64];
    const float4* sWe4 = (const float4*)sWe;   // [k][8] float4
    const float2* sWp2 = (const float2*)sWp;   // [k][24] float2

#pragma unroll 8
    for (int k = 0; k < 64; ++k) {
        float xk = xv[k];                       // broadcast within group
        float4 we = sWe4[k * 8 + t];            // channels 4t..4t+4
        accE[0] = fmaf(xk, we.x, accE[0]);
        accE[1] = fmaf(xk, we.y, accE[1]);
        accE[2] = fmaf(xk, we.z, accE[2]);
        accE[3] = fmaf(xk, we.w, accE[3]);
        float2 w0 = sWp2[k * 24 + t * 3];       // channels 6t..6t+6
        float2 w1 = sWp2[k * 24 + t * 3 + 1];
        float2 w2 = sWp2[k * 24 + t * 3 + 2];
        accP[0] = fmaf(xk, w0.x, accP[0]);
        accP[1] = fmaf(xk, w0.y, accP[1]);
        accP[2] = fmaf(xk, w1.x, accP[2]);
        accP[3] = fmaf(xk, w1.y, accP[3]);
        accP[4] = fmaf(xk, w2.x, accP[4]);
        accP[5] = fmaf(xk, w2.y, accP[5]);
    }

    float dg;
    if (DEG_FROM_CSR) dg = (float)(rowstart[v + 1] - rowstart[v]);
    else              dg = degf[v];
    float dinv = dg > 0.f ? 1.0f / sqrtf(dg) : 0.f;
    float ea0 = easum[2 * v], ea1 = easum[2 * v + 1];

    float* fo = femb + v * 112;
    // ego channels 4t..4t+4
    {
        float4 e;
        e.x = fmaxf(accE[0] + sbe[4 * t + 0], 0.f);
        e.y = fmaxf(accE[1] + sbe[4 * t + 1], 0.f);
        e.z = fmaxf(accE[2] + sbe[4 * t + 2], 0.f);
        e.w = fmaxf(accE[3] + sbe[4 * t + 3], 0.f);
        ((float4*)fo)[t] = e;
    }
    // channels 32..47 (eagg) by t<4; 48..63 (dinv*h2) by t>=4
    if (t < 4) {
        float4 gv = ((const float4*)(eagg + v * 16))[t];
        ((float4*)fo)[8 + t] = gv;
    } else {
        int tt = t - 4;
        float4 hv = ((const float4*)(h2 + v * 16))[tt];
        hv.x *= dinv; hv.y *= dinv; hv.z *= dinv; hv.w *= dinv;
        ((float4*)fo)[12 + tt] = hv;
    }
    // peer channels 6t..6t+6 (offset 64)
#pragma unroll
    for (int i = 0; i < 6; ++i) {
        int c = 6 * t + i;
        float tv = dg * (accP[i] + sbp[c]) + fmaf(ea0, sWpe[c], ea1 * sWpe[48 + c]);
        fo[64 + c] = fmaxf(dinv * tv, 0.f);
    }
}

__global__ __launch_bounds__(256) void k_nodeB(
    const float* __restrict__ femb,
    const float* __restrict__ W_emb, const float* __restrict__ b_emb,
    const float* __restrict__ bn_g, const float* __restrict__ bn_b,
    const float* __restrict__ bn_m, const float* __restrict__ bn_v,
    const float* __restrict__ W0, const float* __restrict__ b0,
    const float* __restrict__ W1, const float* __restrict__ b1,
    float* __restrict__ out, int nN) {
    __shared__ __align__(16) float sW[112 * 64];   // W_emb [k][64]
    __shared__ __align__(16) float sf[32 * 112];   // femb tile (32 nodes)
    __shared__ float sbias[64], sScale[64], sShift[64], sW0[64], sW1[64];
    for (int i = threadIdx.x; i < 112 * 16; i += 256)
        ((float4*)sW)[i] = ((const float4*)W_emb)[i];
    if (threadIdx.x < 64) {
        int j = threadIdx.x;
        sbias[j] = b_emb[j];
        float rstd = 1.0f / sqrtf(bn_v[j] + 1e-5f);
        float sc = bn_g[j] * rstd;
        sScale[j] = sc;
        sShift[j] = bn_b[j] - bn_m[j] * sc;
        sW0[j] = W0[j];
        sW1[j] = W1[j];
    }
    long long base = (long long)blockIdx.x * 32;
    {
        int nv = (int)min(32LL, (long long)nN - base);
        if (nv > 0) {
            const float4* fs = (const float4*)(femb + base * 112);
            int lim = nv * 28;   // 28 float4 per node
            for (int i = threadIdx.x; i < lim; i += 256)
                ((float4*)sf)[i] = fs[i];
        }
    }
    __syncthreads();

    int g = threadIdx.x >> 3;
    int t = threadIdx.x & 7;
    long long v = base + g;
    if (v >= nN) return;

    float acc[8];
#pragma unroll
    for (int j = 0; j < 8; ++j) acc[j] = 0.f;

    const float* fv = &sf[g * 112];
    const float4* sW4 = (const float4*)sW;   // [k][16] float4

#pragma unroll 8
    for (int k = 0; k < 112; ++k) {
        float f = fv[k];                       // broadcast within group
        float4 wa = sW4[k * 16 + t * 2];       // channels 8t..8t+4
        float4 wb = sW4[k * 16 + t * 2 + 1];   // channels 8t+4..8t+8
        acc[0] = fmaf(f, wa.x, acc[0]);
        acc[1] = fmaf(f, wa.y, acc[1]);
        acc[2] = fmaf(f, wa.z, acc[2]);
        acc[3] = fmaf(f, wa.w, acc[3]);
        acc[4] = fmaf(f, wb.x, acc[4]);
        acc[5] = fmaf(f, wb.y, acc[5]);
        acc[6] = fmaf(f, wb.z, acc[6]);
        acc[7] = fmaf(f, wb.w, acc[7]);
    }

    float y0 = 0.f, y1 = 0.f;
#pragma unroll
    for (int j = 0; j < 8; ++j) {
        int c = 8 * t + j;
        float e = fmaxf(acc[j] + sbias[c], 0.f);
        e = fmaf(e, sScale[c], sShift[c]);   // BN inference affine
        e = tanhf(e);
        acc[j] = e;
        y0 = fmaf(e, sW0[c], y0);
        y1 = fmaf(e, sW1[c], y1);
    }
    // reduce y0/y1 across the 8-lane group (xor masks stay within group)
#pragma unroll
    for (int off = 1; off < 8; off <<= 1) {
        y0 += __shfl_xor(y0, off);
        y1 += __shfl_xor(y1, off);
    }

    float4* o4 = (float4*)(out + 2LL * nN + v * 64 + t * 8);
    o4[0] = make_float4(acc[0], acc[1], acc[2], acc[3]);
    o4[1] = make_float4(acc[4], acc[5], acc[6], acc[7]);
    if (t == 0) {
        out[v] = y0 + b0[0];
        out[nN + v] = y1 + b1[0];
    }
}

// ================================ launch ===================================

extern "C" void kernel_launch(void* const* d_in, const int* in_sizes, int n_in,
                              void* d_out, int out_size, void* d_ws, size_t ws_size,
                              hipStream_t stream) {
    const float* x      = (const float*)d_in[0];
    const float* ea     = (const float*)d_in[1];
    const int*   src    = (const int*)d_in[3];
    const int*   dst    = (const int*)d_in[4];
    const float* W_peer = (const float*)d_in[5];
    const float* b_peer = (const float*)d_in[6];
    const float* W_ego  = (const float*)d_in[7];
    const float* b_ego  = (const float*)d_in[8];
    const float* W_edge = (const float*)d_in[9];
    const float* b_edge = (const float*)d_in[10];
    const float* W_emb  = (const float*)d_in[11];
    const float* b_emb  = (const float*)d_in[12];
    const float* bn_g   = (const float*)d_in[13];
    const float* bn_b   = (const float*)d_in[14];
    const float* bn_m   = (const float*)d_in[15];
    const float* bn_v   = (const float*)d_in[16];
    const float* W0     = (const float*)d_in[17];
    const float* b0     = (const float*)d_in[18];
    const float* W1     = (const float*)d_in[19];
    const float* b1     = (const float*)d_in[20];

    int nE = in_sizes[3];
    int nN = in_sizes[2];

    int nABlocks = (nN + 31) / 32;            // node kernels: 32 nodes/block
    int ngBlocks = (16 * nN + 255) / 256;     // 16-thread-per-node kernels
    int eBlocks1 = (nE + 255) / 256;          // 1-thread-per-edge kernels

    // tier 1 fixed region: counts N | rowstart N+4 | eagg 16N | easum 2N |
    // h2 16N = 36N+4 elems
    size_t fixed1   = (size_t)36 * nN + 4;
    size_t fixed1Al = (fixed1 + 3) & ~(size_t)3;
    size_t regElems = 5ULL * nE + 4;  // rank E + payload 4E (+align slop)
    size_t fembEl   = (size_t)112 * nN;
    size_t t1El     = fixed1Al + (regElems > fembEl ? regElems : fembEl);
    // tier 2 fixed region: 37N+4 elems
    size_t fixed2   = (size_t)37 * nN + 4;
    size_t fixed2Al = (fixed2 + 3) & ~(size_t)3;
    size_t reg2     = 4ULL * nE + 4;
    size_t t2El     = fixed2Al + (reg2 > fembEl ? reg2 : fembEl);

    if (ws_size >= 4 * t1El) {
        // ---------------- tier 1: rank-based, atomic-free fill ----------------
        int*   wsi      = (int*)d_ws;
        int*   counts   = wsi;                        // N
        int*   rowstart = wsi + nN;                   // N+1 (pad to N+4)
        float* eagg     = (float*)(wsi + 2 * nN + 4); // 16N
        float* easum    = eagg + 16LL * nN;           // 2N
        float* h2       = easum + 2LL * nN;           // 16N
        int*   rank     = wsi + fixed1Al;             // E
        size_t payOff   = (fixed1Al + (size_t)nE + 3) & ~(size_t)3;
        int4*  payload  = (int4*)(wsi + payOff);      // E x 16B
        float* femb     = (float*)(wsi + fixed1Al);   // 112N (overlays rank/payload)

        hipMemsetAsync(counts, 0, sizeof(int) * (size_t)nN, stream);
        k_countR<<<eBlocks1, 256, 0, stream>>>(dst, counts, rank, nE);
        k_scan<false><<<1, 1024, 0, stream>>>(counts, rowstart, nullptr, nN, nE);
        k_fillR<<<eBlocks1, 256, 0, stream>>>(dst, src, ea, rank, rowstart,
                                              payload, nE);
        k_aggP1<<<ngBlocks, 256, 0, stream>>>(payload, rowstart, W_edge, b_edge,
                                              eagg, easum, nN);
        k_aggP2<<<ngBlocks, 256, 0, stream>>>(payload, rowstart, eagg, h2, nN);
        // payload/rank dead from here; femb overlays them (stream-ordered)
        k_nodeA<true><<<nABlocks, 256, 0, stream>>>(x, W_ego, b_ego, W_peer, b_peer,
                                                    nullptr, rowstart, easum,
                                                    eagg, h2, femb, nN);
        k_nodeB<<<nABlocks, 256, 0, stream>>>(femb, W_emb, b_emb, bn_g, bn_b, bn_m,
                                              bn_v, W0, b0, W1, b1, (float*)d_out, nN);
    } else if (ws_size >= 4 * t2El) {
        // ---------------- tier 2: cursor + atomic fill (R5) ----------------
        int*   wsi      = (int*)d_ws;
        int*   counts   = wsi;                        // N
        int*   rowstart = wsi + nN;                   // N+1 (pad to N+4)
        int*   cursor   = wsi + 2 * nN + 4;           // N
        float* eagg     = (float*)(wsi + 3 * nN + 4); // 16N
        float* easum    = eagg + 16LL * nN;           // 2N
        float* h2       = easum + 2LL * nN;           // 16N
        int4*  payload  = (int4*)(wsi + fixed2Al);    // E x 16B
        float* femb     = (float*)(wsi + fixed2Al);   // overlays payload

        hipMemsetAsync(counts, 0, sizeof(int) * (size_t)nN, stream);
        k_count<<<eBlocks1, 256, 0, stream>>>(dst, counts, nE);
        k_scan<true><<<1, 1024, 0, stream>>>(counts, rowstart, cursor, nN, nE);
        k_fillP<<<eBlocks1, 256, 0, stream>>>(dst, src, ea, cursor, payload, nE);
        k_aggP1<<<ngBlocks, 256, 0, stream>>>(payload, rowstart, W_edge, b_edge,
                                              eagg, easum, nN);
        k_aggP2<<<ngBlocks, 256, 0, stream>>>(payload, rowstart, eagg, h2, nN);
        k_nodeA<true><<<nABlocks, 256, 0, stream>>>(x, W_ego, b_ego, W_peer, b_peer,
                                                    nullptr, rowstart, easum,
                                                    eagg, h2, femb, nN);
        k_nodeB<<<nABlocks, 256, 0, stream>>>(femb, W_emb, b_emb, bn_g, bn_b, bn_m,
                                              bn_v, W0, b0, W1, b1, (float*)d_out, nN);
    } else {
        // ---------------- tier 3: pure-atomic edges ----------------
        float* wsf   = (float*)d_ws;
        float* deg   = wsf;                  // N
        float* easum = wsf + nN;             // 2N
        float* eagg  = wsf + 3LL * nN;       // 16N
        float* h2    = wsf + 19LL * nN;      // 16N
        float* femb  = wsf + 35LL * nN;      // 112N

        hipMemsetAsync(wsf, 0, sizeof(float) * 35ULL * nN, stream);
        const int eBlocks = 2048;
        k_edge1<<<eBlocks, 256, 0, stream>>>(ea, dst, W_edge, b_edge, deg, easum,
                                             eagg, nE);
        k_edge2<<<eBlocks, 256, 0, stream>>>(src, dst, eagg, h2, nE);
        k_nodeA<false><<<nABlocks, 256, 0, stream>>>(x, W_ego, b_ego, W_peer, b_peer,
                                                     deg, nullptr, easum,
                                                     eagg, h2, femb, nN);
        k_nodeB<<<nABlocks, 256, 0, stream>>>(femb, W_emb, b_emb, bn_g, bn_b, bn_m,
                                              bn_v, W0, b0, W1, b1, (float*)d_out, nN);
    }
}

// Round 15
// 353.654 us; speedup vs baseline: 8.8832x; 1.1742x over previous
//
#include <hip/hip_runtime.h>
#include <math.h>

// ---------------------------------------------------------------------------
// GNN TLearner forward, MI355X.
// R14 = R12 resubmitted (R13/R14 benches were infra failures; scan fix
//       unvalidated on hardware).
// R12: replace the single-block k_scan (78us, 0.15% occupancy, serial
//      strided loads) with a two-level multi-block scan:
//      k_bsum (196 blk) -> k_scanb (1 blk over 196 sums) -> k_scatter (196 blk).
//      rowstart values bit-identical. bsum/bbase scratch lives at the head of
//      the overlay region (dead before femb overlays it).
// Node kernels (R11: 8 thr/node, 32 nodes/block), CSR build, aggs unchanged.
//
// Algebra (audited R3): peer MLP folded to node level; 2-hop deg_inv factored;
// relu(f_emb) dropped (all components >=0); deg = rowstart[v+1]-rowstart[v].
//
// Tier1 ws (4B elems):
//   counts[N] | rowstart[N+4] | eagg[16N] | easum[2N] | h2[16N]   (= 36N+4)
//   then REGION{ scanTmp[~2*ceil(N/256)+8] | rank[E] | payload[4E] }
//   overlaid later by femb[112N]
// out layout (floats): y0[N] | y1[N] | emb[64N]
// ---------------------------------------------------------------------------

// ============================ CSR-build kernels ============================

__global__ void k_countR(const int* __restrict__ dst, int* __restrict__ counts,
                         int* __restrict__ rank, int nE) {
    int e = blockIdx.x * blockDim.x + threadIdx.x;
    if (e < nE) rank[e] = atomicAdd(&counts[dst[e]], 1);
}

__global__ void k_count(const int* __restrict__ dst, int* __restrict__ counts,
                        int nE) {
    int e = blockIdx.x * blockDim.x + threadIdx.x;
    if (e < nE) atomicAdd(&counts[dst[e]], 1);
}

// -------- two-level scan: bsum -> scanb -> scatter --------

__global__ __launch_bounds__(256) void k_bsum(const int* __restrict__ counts,
                                              int* __restrict__ bsum, int nN) {
    __shared__ int s[256];
    int i = blockIdx.x * 256 + threadIdx.x;
    int c = (i < nN) ? counts[i] : 0;
    s[threadIdx.x] = c;
    __syncthreads();
#pragma unroll
    for (int off = 128; off > 0; off >>= 1) {
        if (threadIdx.x < off) s[threadIdx.x] += s[threadIdx.x + off];
        __syncthreads();
    }
    if (threadIdx.x == 0) bsum[blockIdx.x] = s[0];
}

// single block over nb block-sums (nb ~ N/256, tiny)
__global__ __launch_bounds__(1024) void k_scanb(const int* __restrict__ bsum,
                                                int* __restrict__ bbase, int nb,
                                                int* __restrict__ rowstart,
                                                int nN, int nE) {
    __shared__ int s[1024];
    int t = threadIdx.x;
    int C = (nb + 1023) / 1024;
    int lo = min(t * C, nb), hi = min(lo + C, nb);
    int sum = 0;
    for (int i = lo; i < hi; ++i) sum += bsum[i];
    s[t] = sum;
    __syncthreads();
    for (int off = 1; off < 1024; off <<= 1) {
        int v = (t >= off) ? s[t - off] : 0;
        __syncthreads();
        s[t] += v;
        __syncthreads();
    }
    int run = (t == 0) ? 0 : s[t - 1];
    for (int i = lo; i < hi; ++i) {
        bbase[i] = run;
        run += bsum[i];
    }
    if (t == 0) rowstart[nN] = nE;
}

template <bool WRITE_CURSOR>
__global__ __launch_bounds__(256) void k_scatter(const int* __restrict__ counts,
                                                 const int* __restrict__ bbase,
                                                 int* __restrict__ rowstart,
                                                 int* __restrict__ cursor,
                                                 int nN) {
    __shared__ int s[256];
    int i = blockIdx.x * 256 + threadIdx.x;
    int c = (i < nN) ? counts[i] : 0;
    s[threadIdx.x] = c;
    __syncthreads();
#pragma unroll
    for (int off = 1; off < 256; off <<= 1) {
        int v = (threadIdx.x >= off) ? s[threadIdx.x - off] : 0;
        __syncthreads();
        s[threadIdx.x] += v;
        __syncthreads();
    }
    if (i < nN) {
        int r = bbase[blockIdx.x] + s[threadIdx.x] - c;   // exclusive
        rowstart[i] = r;
        if (WRITE_CURSOR) cursor[i] = r;
    }
}

// ============================ fill variants ================================

__global__ void k_fillR(const int* __restrict__ dst, const int* __restrict__ src,
                        const float* __restrict__ ea, const int* __restrict__ rank,
                        const int* __restrict__ rowstart,
                        int4* __restrict__ payload, int nE) {
    int e = blockIdx.x * blockDim.x + threadIdx.x;
    if (e < nE) {
        float2 eav = ((const float2*)ea)[e];   // coalesced 8B
        int d = dst[e];                        // coalesced 4B
        int slot = rowstart[d] + rank[e];      // L2 probe + coalesced
        int4 p;
        p.x = __float_as_int(eav.x);
        p.y = __float_as_int(eav.y);
        p.z = src[e];
        p.w = 0;
        payload[slot] = p;                     // one 16B store (fire-and-forget)
    }
}

__global__ void k_fillP(const int* __restrict__ dst, const int* __restrict__ src,
                        const float* __restrict__ ea, int* __restrict__ cursor,
                        int4* __restrict__ payload, int nE) {
    int e = blockIdx.x * blockDim.x + threadIdx.x;
    if (e < nE) {
        float2 eav = ((const float2*)ea)[e];
        int sn = src[e];
        int slot = atomicAdd(&cursor[dst[e]], 1);
        int4 p;
        p.x = __float_as_int(eav.x);
        p.y = __float_as_int(eav.y);
        p.z = sn;
        p.w = 0;
        payload[slot] = p;
    }
}

// ============================ aggregation ==================================

__global__ void k_aggP1(const int4* __restrict__ payload,
                        const int* __restrict__ rowstart,
                        const float* __restrict__ We, const float* __restrict__ be,
                        float* __restrict__ eagg, float* __restrict__ easum,
                        int nN) {
    __shared__ float w[48];   // [0..15]=We row0, [16..31]=We row1, [32..47]=be
    if (threadIdx.x < 32) w[threadIdx.x] = We[threadIdx.x];
    else if (threadIdx.x < 48) w[threadIdx.x] = be[threadIdx.x - 32];
    __syncthreads();
    int gid = blockIdx.x * blockDim.x + threadIdx.x;
    int v = gid >> 4, j = gid & 15;
    if (v >= nN) return;
    int s0 = rowstart[v], s1 = rowstart[v + 1];
    float acc = 0.f, aE = 0.f;
    for (int s = s0; s < s1; ++s) {
        int4 p = payload[s];
        float ea0 = __int_as_float(p.x), ea1 = __int_as_float(p.y);
        acc += fmaxf(fmaf(ea0, w[j], fmaf(ea1, w[16 + j], w[32 + j])), 0.f);
        if (j == 0) aE += ea0;
        else if (j == 1) aE += ea1;
    }
    eagg[v * 16 + j] = acc;
    if (j == 0) easum[2 * v] = aE;
    else if (j == 1) easum[2 * v + 1] = aE;
}

__global__ void k_aggP2(const int4* __restrict__ payload,
                        const int* __restrict__ rowstart,
                        const float* __restrict__ eagg, float* __restrict__ h2,
                        int nN) {
    int gid = blockIdx.x * blockDim.x + threadIdx.x;
    int v = gid >> 4, j = gid & 15;
    if (v >= nN) return;
    int s0 = rowstart[v], s1 = rowstart[v + 1];
    float acc = 0.f;
    for (int s = s0; s < s1; ++s) {
        int sn = payload[s].z;                 // sequential (stride 16B)
        acc += eagg[sn * 16 + j];              // 64B line per 16-lane group
    }
    h2[v * 16 + j] = acc;
}

// ========================= atomic tier (fallback) ==========================

__global__ void k_edge1(const float* __restrict__ ea, const int* __restrict__ dst,
                        const float* __restrict__ We, const float* __restrict__ be,
                        float* __restrict__ deg, float* __restrict__ easum,
                        float* __restrict__ eagg, int nE) {
    __shared__ float w[48];
    if (threadIdx.x < 32) w[threadIdx.x] = We[threadIdx.x];
    else if (threadIdx.x < 48) w[threadIdx.x] = be[threadIdx.x - 32];
    __syncthreads();
    const float2* ea2 = (const float2*)ea;
    long long stride = (long long)gridDim.x * blockDim.x;
    for (long long gid = (long long)blockIdx.x * blockDim.x + threadIdx.x;
         gid < 16LL * nE; gid += stride) {
        int e = (int)(gid >> 4);
        int j = (int)(gid & 15);
        int d = dst[e];
        float2 eav = ea2[e];
        float h = fmaxf(fmaf(eav.x, w[j], fmaf(eav.y, w[16 + j], w[32 + j])), 0.f);
        atomicAdd(&eagg[d * 16 + j], h);
        if (j == 0)      atomicAdd(&deg[d], 1.0f);
        else if (j == 1) atomicAdd(&easum[2 * d], eav.x);
        else if (j == 2) atomicAdd(&easum[2 * d + 1], eav.y);
    }
}

__global__ void k_edge2(const int* __restrict__ src, const int* __restrict__ dst,
                        const float* __restrict__ eagg, float* __restrict__ h2,
                        int nE) {
    long long stride = (long long)gridDim.x * blockDim.x;
    for (long long gid = (long long)blockIdx.x * blockDim.x + threadIdx.x;
         gid < 16LL * nE; gid += stride) {
        int e = (int)(gid >> 4);
        int j = (int)(gid & 15);
        atomicAdd(&h2[dst[e] * 16 + j], eagg[src[e] * 16 + j]);
    }
}

// ============================= node kernels ================================
// 8 threads per node, 32 nodes per 256-thread block -> 1563 blocks @ N=50000.

template <bool DEG_FROM_CSR>
__global__ __launch_bounds__(256) void k_nodeA(
    const float* __restrict__ x,
    const float* __restrict__ W_ego, const float* __restrict__ b_ego,
    const float* __restrict__ W_peer, const float* __restrict__ b_peer,
    const float* __restrict__ degf, const int* __restrict__ rowstart,
    const float* __restrict__ easum,
    const float* __restrict__ eagg, const float* __restrict__ h2,
    float* __restrict__ femb, int nN) {
    __shared__ __align__(16) float sWe[64 * 32];   // W_ego [k][32]
    __shared__ __align__(16) float sWp[64 * 48];   // W_peer rows 0..63 (x part)
    __shared__ __align__(16) float sx[32 * 64];    // x tile (32 nodes)
    __shared__ float sWpe[96];                     // W_peer rows 64,65
    __shared__ float sbe[32];
    __shared__ float sbp[48];
    for (int i = threadIdx.x; i < 64 * 32; i += 256) sWe[i] = W_ego[i];
    for (int i = threadIdx.x; i < 64 * 48; i += 256) sWp[i] = W_peer[i];
    if (threadIdx.x < 96) sWpe[threadIdx.x] = W_peer[64 * 48 + threadIdx.x];
    if (threadIdx.x < 32) sbe[threadIdx.x] = b_ego[threadIdx.x];
    if (threadIdx.x < 48) sbp[threadIdx.x] = b_peer[threadIdx.x];

    long long base = (long long)blockIdx.x * 32;
    {
        int nv = (int)min(32LL, (long long)nN - base);
        if (nv > 0) {
            const float4* xs = (const float4*)(x + base * 64);
            int lim = nv * 16;   // 16 float4 per node
            for (int i = threadIdx.x; i < lim; i += 256)
                ((float4*)sx)[i] = xs[i];
        }
    }
    __syncthreads();

    int g = threadIdx.x >> 3;       // node group 0..31
    int t = threadIdx.x & 7;        // lane-in-group 0..7
    long long v = base + g;
    if (v >= nN) return;

    float accE[4] = {0.f, 0.f, 0.f, 0.f};
    float accP[6] = {0.f, 0.f, 0.f, 0.f, 0.f, 0.f};
    const float* xv = &sx[g * 64];
    const float4* sWe4 = (const float4*)sWe;   // [k][8] float4
    const float2* sWp2 = (const float2*)sWp;   // [k][24] float2

#pragma unroll 8
    for (int k = 0; k < 64; ++k) {
        float xk = xv[k];                       // broadcast within group
        float4 we = sWe4[k * 8 + t];            // channels 4t..4t+4
        accE[0] = fmaf(xk, we.x, accE[0]);
        accE[1] = fmaf(xk, we.y, accE[1]);
        accE[2] = fmaf(xk, we.z, accE[2]);
        accE[3] = fmaf(xk, we.w, accE[3]);
        float2 w0 = sWp2[k * 24 + t * 3];       // channels 6t..6t+6
        float2 w1 = sWp2[k * 24 + t * 3 + 1];
        float2 w2 = sWp2[k * 24 + t * 3 + 2];
        accP[0] = fmaf(xk, w0.x, accP[0]);
        accP[1] = fmaf(xk, w0.y, accP[1]);
        accP[2] = fmaf(xk, w1.x, accP[2]);
        accP[3] = fmaf(xk, w1.y, accP[3]);
        accP[4] = fmaf(xk, w2.x, accP[4]);
        accP[5] = fmaf(xk, w2.y, accP[5]);
    }

    float dg;
    if (DEG_FROM_CSR) dg = (float)(rowstart[v + 1] - rowstart[v]);
    else              dg = degf[v];
    float dinv = dg > 0.f ? 1.0f / sqrtf(dg) : 0.f;
    float ea0 = easum[2 * v], ea1 = easum[2 * v + 1];

    float* fo = femb + v * 112;
    // ego channels 4t..4t+4
    {
        float4 e;
        e.x = fmaxf(accE[0] + sbe[4 * t + 0], 0.f);
        e.y = fmaxf(accE[1] + sbe[4 * t + 1], 0.f);
        e.z = fmaxf(accE[2] + sbe[4 * t + 2], 0.f);
        e.w = fmaxf(accE[3] + sbe[4 * t + 3], 0.f);
        ((float4*)fo)[t] = e;
    }
    // channels 32..47 (eagg) by t<4; 48..63 (dinv*h2) by t>=4
    if (t < 4) {
        float4 gv = ((const float4*)(eagg + v * 16))[t];
        ((float4*)fo)[8 + t] = gv;
    } else {
        int tt = t - 4;
        float4 hv = ((const float4*)(h2 + v * 16))[tt];
        hv.x *= dinv; hv.y *= dinv; hv.z *= dinv; hv.w *= dinv;
        ((float4*)fo)[12 + tt] = hv;
    }
    // peer channels 6t..6t+6 (offset 64)
#pragma unroll
    for (int i = 0; i < 6; ++i) {
        int c = 6 * t + i;
        float tv = dg * (accP[i] + sbp[c]) + fmaf(ea0, sWpe[c], ea1 * sWpe[48 + c]);
        fo[64 + c] = fmaxf(dinv * tv, 0.f);
    }
}

__global__ __launch_bounds__(256) void k_nodeB(
    const float* __restrict__ femb,
    const float* __restrict__ W_emb, const float* __restrict__ b_emb,
    const float* __restrict__ bn_g, const float* __restrict__ bn_b,
    const float* __restrict__ bn_m, const float* __restrict__ bn_v,
    const float* __restrict__ W0, const float* __restrict__ b0,
    const float* __restrict__ W1, const float* __restrict__ b1,
    float* __restrict__ out, int nN) {
    __shared__ __align__(16) float sW[112 * 64];   // W_emb [k][64]
    __shared__ __align__(16) float sf[32 * 112];   // femb tile (32 nodes)
    __shared__ float sbias[64], sScale[64], sShift[64], sW0[64], sW1[64];
    for (int i = threadIdx.x; i < 112 * 16; i += 256)
        ((float4*)sW)[i] = ((const float4*)W_emb)[i];
    if (threadIdx.x < 64) {
        int j = threadIdx.x;
        sbias[j] = b_emb[j];
        float rstd = 1.0f / sqrtf(bn_v[j] + 1e-5f);
        float sc = bn_g[j] * rstd;
        sScale[j] = sc;
        sShift[j] = bn_b[j] - bn_m[j] * sc;
        sW0[j] = W0[j];
        sW1[j] = W1[j];
    }
    long long base = (long long)blockIdx.x * 32;
    {
        int nv = (int)min(32LL, (long long)nN - base);
        if (nv > 0) {
            const float4* fs = (const float4*)(femb + base * 112);
            int lim = nv * 28;   // 28 float4 per node
            for (int i = threadIdx.x; i < lim; i += 256)
                ((float4*)sf)[i] = fs[i];
        }
    }
    __syncthreads();

    int g = threadIdx.x >> 3;
    int t = threadIdx.x & 7;
    long long v = base + g;
    if (v >= nN) return;

    float acc[8];
#pragma unroll
    for (int j = 0; j < 8; ++j) acc[j] = 0.f;

    const float* fv = &sf[g * 112];
    const float4* sW4 = (const float4*)sW;   // [k][16] float4

#pragma unroll 8
    for (int k = 0; k < 112; ++k) {
        float f = fv[k];                       // broadcast within group
        float4 wa = sW4[k * 16 + t * 2];       // channels 8t..8t+4
        float4 wb = sW4[k * 16 + t * 2 + 1];   // channels 8t+4..8t+8
        acc[0] = fmaf(f, wa.x, acc[0]);
        acc[1] = fmaf(f, wa.y, acc[1]);
        acc[2] = fmaf(f, wa.z, acc[2]);
        acc[3] = fmaf(f, wa.w, acc[3]);
        acc[4] = fmaf(f, wb.x, acc[4]);
        acc[5] = fmaf(f, wb.y, acc[5]);
        acc[6] = fmaf(f, wb.z, acc[6]);
        acc[7] = fmaf(f, wb.w, acc[7]);
    }

    float y0 = 0.f, y1 = 0.f;
#pragma unroll
    for (int j = 0; j < 8; ++j) {
        int c = 8 * t + j;
        float e = fmaxf(acc[j] + sbias[c], 0.f);
        e = fmaf(e, sScale[c], sShift[c]);   // BN inference affine
        e = tanhf(e);
        acc[j] = e;
        y0 = fmaf(e, sW0[c], y0);
        y1 = fmaf(e, sW1[c], y1);
    }
    // reduce y0/y1 across the 8-lane group (xor masks stay within group)
#pragma unroll
    for (int off = 1; off < 8; off <<= 1) {
        y0 += __shfl_xor(y0, off);
        y1 += __shfl_xor(y1, off);
    }

    float4* o4 = (float4*)(out + 2LL * nN + v * 64 + t * 8);
    o4[0] = make_float4(acc[0], acc[1], acc[2], acc[3]);
    o4[1] = make_float4(acc[4], acc[5], acc[6], acc[7]);
    if (t == 0) {
        out[v] = y0 + b0[0];
        out[nN + v] = y1 + b1[0];
    }
}

// ================================ launch ===================================

extern "C" void kernel_launch(void* const* d_in, const int* in_sizes, int n_in,
                              void* d_out, int out_size, void* d_ws, size_t ws_size,
                              hipStream_t stream) {
    const float* x      = (const float*)d_in[0];
    const float* ea     = (const float*)d_in[1];
    const int*   src    = (const int*)d_in[3];
    const int*   dst    = (const int*)d_in[4];
    const float* W_peer = (const float*)d_in[5];
    const float* b_peer = (const float*)d_in[6];
    const float* W_ego  = (const float*)d_in[7];
    const float* b_ego  = (const float*)d_in[8];
    const float* W_edge = (const float*)d_in[9];
    const float* b_edge = (const float*)d_in[10];
    const float* W_emb  = (const float*)d_in[11];
    const float* b_emb  = (const float*)d_in[12];
    const float* bn_g   = (const float*)d_in[13];
    const float* bn_b   = (const float*)d_in[14];
    const float* bn_m   = (const float*)d_in[15];
    const float* bn_v   = (const float*)d_in[16];
    const float* W0     = (const float*)d_in[17];
    const float* b0     = (const float*)d_in[18];
    const float* W1     = (const float*)d_in[19];
    const float* b1     = (const float*)d_in[20];

    int nE = in_sizes[3];
    int nN = in_sizes[2];

    int nABlocks = (nN + 31) / 32;            // node kernels: 32 nodes/block
    int ngBlocks = (16 * nN + 255) / 256;     // 16-thread-per-node kernels
    int eBlocks1 = (nE + 255) / 256;          // 1-thread-per-edge kernels
    int nb       = (nN + 255) / 256;          // scan blocks

    // scan scratch: bsum[nb] | bbase[nb], padded to 4
    size_t scanEl = ((size_t)(2 * nb + 8) + 3) & ~(size_t)3;

    // tier 1 fixed region: counts N | rowstart N+4 | eagg 16N | easum 2N |
    // h2 16N = 36N+4 elems
    size_t fixed1   = (size_t)36 * nN + 4;
    size_t fixed1Al = (fixed1 + 3) & ~(size_t)3;
    size_t regElems = scanEl + 5ULL * nE + 4;  // scanTmp + rank + payload
    size_t fembEl   = (size_t)112 * nN;
    size_t t1El     = fixed1Al + (regElems > fembEl ? regElems : fembEl);
    // tier 2 fixed region: 37N+4 elems
    size_t fixed2   = (size_t)37 * nN + 4;
    size_t fixed2Al = (fixed2 + 3) & ~(size_t)3;
    size_t reg2     = scanEl + 4ULL * nE + 4;
    size_t t2El     = fixed2Al + (reg2 > fembEl ? reg2 : fembEl);

    if (ws_size >= 4 * t1El) {
        // ---------------- tier 1: rank-based, atomic-free fill ----------------
        int*   wsi      = (int*)d_ws;
        int*   counts   = wsi;                        // N
        int*   rowstart = wsi + nN;                   // N+1 (pad to N+4)
        float* eagg     = (float*)(wsi + 2 * nN + 4); // 16N
        float* easum    = eagg + 16LL * nN;           // 2N
        float* h2       = easum + 2LL * nN;           // 16N
        int*   bsum     = wsi + fixed1Al;             // nb
        int*   bbase    = bsum + nb;                  // nb
        int*   rank     = wsi + fixed1Al + scanEl;    // E
        size_t payOff   = (fixed1Al + scanEl + (size_t)nE + 3) & ~(size_t)3;
        int4*  payload  = (int4*)(wsi + payOff);      // E x 16B
        float* femb     = (float*)(wsi + fixed1Al);   // 112N (overlays scan/rank/payload)

        hipMemsetAsync(counts, 0, sizeof(int) * (size_t)nN, stream);
        k_countR<<<eBlocks1, 256, 0, stream>>>(dst, counts, rank, nE);
        k_bsum<<<nb, 256, 0, stream>>>(counts, bsum, nN);
        k_scanb<<<1, 1024, 0, stream>>>(bsum, bbase, nb, rowstart, nN, nE);
        k_scatter<false><<<nb, 256, 0, stream>>>(counts, bbase, rowstart,
                                                 nullptr, nN);
        k_fillR<<<eBlocks1, 256, 0, stream>>>(dst, src, ea, rank, rowstart,
                                              payload, nE);
        k_aggP1<<<ngBlocks, 256, 0, stream>>>(payload, rowstart, W_edge, b_edge,
                                              eagg, easum, nN);
        k_aggP2<<<ngBlocks, 256, 0, stream>>>(payload, rowstart, eagg, h2, nN);
        // scanTmp/rank/payload dead from here; femb overlays them
        k_nodeA<true><<<nABlocks, 256, 0, stream>>>(x, W_ego, b_ego, W_peer, b_peer,
                                                    nullptr, rowstart, easum,
                                                    eagg, h2, femb, nN);
        k_nodeB<<<nABlocks, 256, 0, stream>>>(femb, W_emb, b_emb, bn_g, bn_b, bn_m,
                                              bn_v, W0, b0, W1, b1, (float*)d_out, nN);
    } else if (ws_size >= 4 * t2El) {
        // ---------------- tier 2: cursor + atomic fill ----------------
        int*   wsi      = (int*)d_ws;
        int*   counts   = wsi;                        // N
        int*   rowstart = wsi + nN;                   // N+1 (pad to N+4)
        int*   cursor   = wsi + 2 * nN + 4;           // N
        float* eagg     = (float*)(wsi + 3 * nN + 4); // 16N
        float* easum    = eagg + 16LL * nN;           // 2N
        float* h2       = easum + 2LL * nN;           // 16N
        int*   bsum     = wsi + fixed2Al;             // nb
        int*   bbase    = bsum + nb;                  // nb
        size_t payOff2  = (fixed2Al + scanEl + 3) & ~(size_t)3;
        int4*  payload  = (int4*)(wsi + payOff2);     // E x 16B
        float* femb     = (float*)(wsi + fixed2Al);   // overlays scan/payload

        hipMemsetAsync(counts, 0, sizeof(int) * (size_t)nN, stream);
        k_count<<<eBlocks1, 256, 0, stream>>>(dst, counts, nE);
        k_bsum<<<nb, 256, 0, stream>>>(counts, bsum, nN);
        k_scanb<<<1, 1024, 0, stream>>>(bsum, bbase, nb, rowstart, nN, nE);
        k_scatter<true><<<nb, 256, 0, stream>>>(counts, bbase, rowstart,
                                                cursor, nN);
        k_fillP<<<eBlocks1, 256, 0, stream>>>(dst, src, ea, cursor, payload, nE);
        k_aggP1<<<ngBlocks, 256, 0, stream>>>(payload, rowstart, W_edge, b_edge,
                                              eagg, easum, nN);
        k_aggP2<<<ngBlocks, 256, 0, stream>>>(payload, rowstart, eagg, h2, nN);
        k_nodeA<true><<<nABlocks, 256, 0, stream>>>(x, W_ego, b_ego, W_peer, b_peer,
                                                    nullptr, rowstart, easum,
                                                    eagg, h2, femb, nN);
        k_nodeB<<<nABlocks, 256, 0, stream>>>(femb, W_emb, b_emb, bn_g, bn_b, bn_m,
                                              bn_v, W0, b0, W1, b1, (float*)d_out, nN);
    } else {
        // ---------------- tier 3: pure-atomic edges ----------------
        float* wsf   = (float*)d_ws;
        float* deg   = wsf;                  // N
        float* easum = wsf + nN;             // 2N
        float* eagg  = wsf + 3LL * nN;       // 16N
        float* h2    = wsf + 19LL * nN;      // 16N
        float* femb  = wsf + 35LL * nN;      // 112N

        hipMemsetAsync(wsf, 0, sizeof(float) * 35ULL * nN, stream);
        const int eBlocks = 2048;
        k_edge1<<<eBlocks, 256, 0, stream>>>(ea, dst, W_edge, b_edge, deg, easum,
                                             eagg, nE);
        k_edge2<<<eBlocks, 256, 0, stream>>>(src, dst, eagg, h2, nE);
        k_nodeA<false><<<nABlocks, 256, 0, stream>>>(x, W_ego, b_ego, W_peer, b_peer,
                                                     deg, nullptr, easum,
                                                     eagg, h2, femb, nN);
        k_nodeB<<<nABlocks, 256, 0, stream>>>(femb, W_emb, b_emb, bn_g, bn_b, bn_m,
                                              bn_v, W0, b0, W1, b1, (float*)d_out, nN);
    }
}